// Round 1
// baseline (62.321 us; speedup 1.0000x reference)
//
#include <hip/hip_runtime.h>

#define S 256
#define E 128
#define H 8
#define D 16
#define TWO_D 32

__device__ __forceinline__ float fast_tanh(float x) {
    // 1 - 2/(e^{2x}+1): safe at both tails (no inf/inf), |x| here is < ~0.3
    float t = __expf(2.0f * x);
    return 1.0f - 2.0f / (t + 1.0f);
}

// Kernel 1: Q/K/V projections for one sequence position per block (128 threads),
// plus the separable transport-MLP precomputes aq, bkb(+bt1), and c.
__global__ __launch_bounds__(128) void k1_proj(
        const float* __restrict__ x,
        const float* __restrict__ Wq, const float* __restrict__ bq,
        const float* __restrict__ Wk, const float* __restrict__ bk,
        const float* __restrict__ Wv, const float* __restrict__ bv,
        const float* __restrict__ Wt1, const float* __restrict__ bt1,
        const float* __restrict__ bt2,
        float* __restrict__ Q, float* __restrict__ Kp, float* __restrict__ V,
        float* __restrict__ aq, float* __restrict__ bkb, float* __restrict__ c) {
    __shared__ float xr[E];
    __shared__ float qr[E];
    __shared__ float kr[E];
    const int s = blockIdx.x;
    const int t = threadIdx.x;

    xr[t] = x[s * E + t];
    __syncthreads();

    float accq = bq[t], acck = bk[t], accv = bv[t];
    const float* wq = Wq + t * E;
    const float* wk = Wk + t * E;
    const float* wv = Wv + t * E;
    #pragma unroll
    for (int i = 0; i < E; i += 4) {
        float4 xv = *(const float4*)&xr[i];
        float4 q4 = *(const float4*)&wq[i];
        float4 k4 = *(const float4*)&wk[i];
        float4 v4 = *(const float4*)&wv[i];
        accq += xv.x * q4.x + xv.y * q4.y + xv.z * q4.z + xv.w * q4.w;
        acck += xv.x * k4.x + xv.y * k4.y + xv.z * k4.z + xv.w * k4.w;
        accv += xv.x * v4.x + xv.y * v4.y + xv.z * v4.z + xv.w * v4.w;
    }
    const int h = t >> 4, d = t & 15;
    Q[h * S * D + s * D + d] = accq;
    Kp[h * S * D + s * D + d] = acck;
    V[h * S * D + s * D + d] = accv;
    qr[t] = accq;
    kr[t] = acck;
    __syncthreads();

    // aq[h][s][j] = sum_d Wt1[j][d]   * Q[h][s][d]
    // bkb[h][s][j]= sum_d Wt1[j][16+d]* K[h][s][d] + bt1[j]
    for (int idx = t; idx < H * TWO_D; idx += 128) {
        const int hh = idx >> 5, j = idx & 31;
        const float* w1 = Wt1 + j * TWO_D;
        float a = 0.f, b = bt1[j];
        #pragma unroll
        for (int dd = 0; dd < D; ++dd) {
            a += w1[dd]      * qr[hh * D + dd];
            b += w1[D + dd]  * kr[hh * D + dd];
        }
        aq[(hh * S + s) * TWO_D + j] = a;
        bkb[(hh * S + s) * TWO_D + j] = b;
    }

    // c[h][s][d] = sum_e bt2[d*16+e] * K[h][s][e]
    {
        float cv = 0.f;
        #pragma unroll
        for (int e2 = 0; e2 < D; ++e2) cv += bt2[d * D + e2] * kr[h * D + e2];
        c[(h * S + s) * D + d] = cv;
    }
}

// Kernel 2 (the heavy one): one wave per (h,k).
// Hbar[j] = mean_q tanh(aq[h][q][j] + bkb[h][k][j]);
// K_out[h][k][d] = sum_e K[h][k][e] * (sum_j Wt2[(d*16+e)][j]*Hbar[j]) + c[h][k][d]
__global__ __launch_bounds__(64) void k2_transport(
        const float* __restrict__ aq, const float* __restrict__ bkb,
        const float* __restrict__ Kp, const float* __restrict__ Wt2,
        const float* __restrict__ c, float* __restrict__ Kout) {
    const int blk = blockIdx.x;
    const int h = blk >> 8, k = blk & 255;
    const int lane = threadIdx.x;
    const int j = lane & 31, half = lane >> 5;

    const float bv = bkb[(h * S + k) * TWO_D + j];
    const float* aqp = aq + (h * S + half * 128) * TWO_D + j;
    float acc = 0.f;
    #pragma unroll 8
    for (int qi = 0; qi < 128; ++qi) {
        acc += fast_tanh(aqp[qi * TWO_D] + bv);
    }
    acc += __shfl_xor(acc, 32);

    __shared__ float hb[TWO_D];
    if (lane < 32) hb[j] = acc * (1.0f / 256.0f);
    __syncthreads();

    // Tail across all 64 lanes: d = lane>>2, e-quad = lane&3
    const int d = lane >> 2, g = lane & 3;
    float p = 0.f;
    #pragma unroll
    for (int eo = 0; eo < 4; ++eo) {
        const int e = g * 4 + eo;
        const float ke = Kp[(h * S + k) * D + e];
        const float* w2 = Wt2 + (d * D + e) * TWO_D;
        float dotv = 0.f;
        #pragma unroll
        for (int jj = 0; jj < TWO_D; ++jj) dotv += w2[jj] * hb[jj];
        p += ke * dotv;
    }
    p += __shfl_xor(p, 1);
    p += __shfl_xor(p, 2);
    if (g == 0) Kout[(h * S + k) * D + d] = p + c[(h * S + k) * D + d];
}

// Kernel 3: attention (scores -> softmax -> PV) + output projection, one block per q.
__global__ __launch_bounds__(256) void k3_attn(
        const float* __restrict__ Q, const float* __restrict__ Kout,
        const float* __restrict__ V, const float* __restrict__ Wo,
        const float* __restrict__ bo, float* __restrict__ out) {
    const int q = blockIdx.x;
    const int t = threadIdx.x;
    __shared__ float qr[E];
    __shared__ float attn[H * S];   // 8 KB
    __shared__ float ctx[E];
    __shared__ float red[H][4];

    if (t < E) qr[t] = Q[(t >> 4) * S * D + q * D + (t & 15)];
    __syncthreads();

    const int k = t;
    const int lane = t & 63, wid = t >> 6;
    float sc[H];
    #pragma unroll
    for (int h = 0; h < H; ++h) {
        const float* ko = Kout + (h * S + k) * D;
        const float* qh = qr + h * D;
        float a = 0.f;
        #pragma unroll
        for (int d = 0; d < D; ++d) a += qh[d] * ko[d];
        sc[h] = a * 0.25f;  // 1/sqrt(16)
    }

    // per-h block max
    #pragma unroll
    for (int h = 0; h < H; ++h) {
        float m = sc[h];
        for (int off = 32; off; off >>= 1) m = fmaxf(m, __shfl_xor(m, off));
        if (lane == 0) red[h][wid] = m;
    }
    __syncthreads();
    float mx[H];
    #pragma unroll
    for (int h = 0; h < H; ++h)
        mx[h] = fmaxf(fmaxf(red[h][0], red[h][1]), fmaxf(red[h][2], red[h][3]));
    __syncthreads();

    // exp + per-h block sum
    #pragma unroll
    for (int h = 0; h < H; ++h) {
        float p = __expf(sc[h] - mx[h]);
        sc[h] = p;
        float ssum = p;
        for (int off = 32; off; off >>= 1) ssum += __shfl_xor(ssum, off);
        if (lane == 0) red[h][wid] = ssum;
    }
    __syncthreads();
    #pragma unroll
    for (int h = 0; h < H; ++h) {
        const float ssum = red[h][0] + red[h][1] + red[h][2] + red[h][3];
        attn[h * S + k] = sc[h] / ssum;
    }
    __syncthreads();

    // ctx[e] = sum_k attn[h][k] * V[h][k][d]
    if (t < E) {
        const int h = t >> 4, d = t & 15;
        const float* vh = V + h * S * D + d;
        const float* at = attn + h * S;
        float a = 0.f;
        #pragma unroll 4
        for (int kk = 0; kk < S; ++kk) a += at[kk] * vh[kk * D];
        ctx[t] = a;
    }
    __syncthreads();

    // y[eo] = bo[eo] + sum_e ctx[e] * Wo[eo][e]
    if (t < E) {
        float y = bo[t];
        const float* wo = Wo + t * E;
        #pragma unroll
        for (int e = 0; e < E; e += 4) {
            float4 c4 = *(const float4*)&ctx[e];
            float4 w4 = *(const float4*)&wo[e];
            y += c4.x * w4.x + c4.y * w4.y + c4.z * w4.z + c4.w * w4.w;
        }
        out[q * E + t] = y;
    }
}

extern "C" void kernel_launch(void* const* d_in, const int* in_sizes, int n_in,
                              void* d_out, int out_size, void* d_ws, size_t ws_size,
                              hipStream_t stream) {
    const float* x   = (const float*)d_in[0];
    const float* Wq  = (const float*)d_in[1];
    const float* bq  = (const float*)d_in[2];
    const float* Wk  = (const float*)d_in[3];
    const float* bk  = (const float*)d_in[4];
    const float* Wv  = (const float*)d_in[5];
    const float* bv  = (const float*)d_in[6];
    const float* Wo  = (const float*)d_in[7];
    const float* bo  = (const float*)d_in[8];
    const float* Wt1 = (const float*)d_in[9];
    const float* bt1 = (const float*)d_in[10];
    const float* Wt2 = (const float*)d_in[11];
    const float* bt2 = (const float*)d_in[12];

    float* ws   = (float*)d_ws;
    float* Q    = ws;                 // 8*256*16 = 32768
    float* Kp   = ws + 32768;         // 32768
    float* V    = ws + 65536;         // 32768
    float* aq   = ws + 98304;         // 8*256*32 = 65536
    float* bkb  = ws + 163840;        // 65536
    float* c    = ws + 229376;        // 32768
    float* Kout = ws + 262144;        // 32768

    k1_proj<<<S, 128, 0, stream>>>(x, Wq, bq, Wk, bk, Wv, bv, Wt1, bt1, bt2,
                                   Q, Kp, V, aq, bkb, c);
    k2_transport<<<H * S, 64, 0, stream>>>(aq, bkb, Kp, Wt2, c, Kout);
    k3_attn<<<S, 256, 0, stream>>>(Q, Kout, V, Wo, bo, (float*)d_out);
}